// Round 1
// 476.514 us; speedup vs baseline: 2.0896x; 2.0896x over previous
//
#include <hip/hip_runtime.h>

constexpr int NN   = 100000;
constexpr int NE   = 3200000;
constexpr int FIN  = 512;
constexpr int FH   = 16;
constexpr int FOUT = 64;

constexpr int BSH = 6;                     // bucket shift (64 nodes/bucket)
constexpr int BSZ = 64;
constexpr int K   = (NN + BSZ - 1) / BSZ;  // 1563 buckets
constexpr int NB  = 512;                   // binning blocks
constexpr int CHUNK = NE / NB;             // 6250 edges per block (exact)
constexpr int CAP = 4096;                  // LDS staging cap per bucket (mean 2048, sigma ~45)

// per-block bucket counts: M[k*NB + b]
__global__ __launch_bounds__(256) void k_cnt(const int* __restrict__ ei, int* __restrict__ M) {
    __shared__ int h[K];
    int t = threadIdx.x, b = blockIdx.x;
    for (int i = t; i < K; i += 256) h[i] = 0;
    __syncthreads();
    int e0 = b * CHUNK;
    for (int e = e0 + t; e < e0 + CHUNK; e += 256)
        atomicAdd(&h[ei[NE + e] >> BSH], 1);
    __syncthreads();
    for (int i = t; i < K; i += 256) M[i * NB + b] = h[i];
}

// per bucket-row exclusive scan over the NB blocks, in place; bucket totals out.
__global__ __launch_bounds__(256) void k_scanM(int* __restrict__ M, int* __restrict__ btot) {
    int k = blockIdx.x, t = threadIdx.x;
    int2* row = (int2*)(M + (size_t)k * NB);
    int2 v = row[t];                       // 256 threads x 2 = NB
    int s = v.x + v.y;
    int lane = t & 63, wid = t >> 6;
    int ps = s;
    #pragma unroll
    for (int off = 1; off < 64; off <<= 1) {
        int u = __shfl_up(ps, off, 64);
        if (lane >= off) ps += u;
    }
    __shared__ int wsum[4];
    if (lane == 63) wsum[wid] = ps;
    __syncthreads();
    int base = 0;
    for (int w = 0; w < wid; ++w) base += wsum[w];
    int excl = base + ps - s;
    int2 o; o.x = excl; o.y = excl + v.x;
    row[t] = o;
    if (t == 255) btot[k] = excl + s;
}

// exclusive scan of bucket totals (K=1563) -> bstart[K+1]; 2 elems/thread
__global__ __launch_bounds__(1024) void k_scanB(const int* __restrict__ btot, int* __restrict__ bstart) {
    int t = threadIdx.x;
    int i0 = 2 * t, i1 = 2 * t + 1;
    int c0 = (i0 < K) ? btot[i0] : 0;
    int c1 = (i1 < K) ? btot[i1] : 0;
    int s = c0 + c1;
    int lane = t & 63, wid = t >> 6;
    int ps = s;
    #pragma unroll
    for (int off = 1; off < 64; off <<= 1) {
        int u = __shfl_up(ps, off, 64);
        if (lane >= off) ps += u;
    }
    __shared__ int wsum[16];
    if (lane == 63) wsum[wid] = ps;
    __syncthreads();
    int base = 0;
    for (int w = 0; w < wid; ++w) base += wsum[w];
    int excl = base + ps - s;
    if (i0 < K) bstart[i0] = excl;
    if (i1 < K) bstart[i1] = excl + c0;
    if (t == 0) bstart[K] = NE;
}

// deterministic scatter: rec1[pos] = (src<<6) | d_local, positions from scans (LDS cursors only)
__global__ __launch_bounds__(256) void k_scatter2(const int* __restrict__ ei,
                                                  const int* __restrict__ M,
                                                  const int* __restrict__ bstart,
                                                  int* __restrict__ rec) {
    __shared__ int cur[K];
    int t = threadIdx.x, b = blockIdx.x;
    for (int i = t; i < K; i += 256) cur[i] = bstart[i] + M[i * NB + b];
    __syncthreads();
    int e0 = b * CHUNK;
    for (int e = e0 + t; e < e0 + CHUNK; e += 256) {
        int s = ei[e];
        int d = ei[NE + e];
        int pos = atomicAdd(&cur[d >> BSH], 1);
        rec[pos] = (s << BSH) | (d & (BSZ - 1));
    }
}

// in-bucket counting sort by d_local -> full CSR by destination node.
// Also emits row_ptr[node] and dis[node] = rsqrt(deg+1) (folds old k_deg_dis).
__global__ __launch_bounds__(256) void k_sort2(const int* __restrict__ rec1,
                                               const int* __restrict__ bstart,
                                               int* __restrict__ rec2,
                                               int* __restrict__ row_ptr,
                                               float* __restrict__ dis) {
    __shared__ int h[BSZ];
    __shared__ int cur[BSZ];
    int t = threadIdx.x, k = blockIdx.x;
    if (t < BSZ) h[t] = 0;
    __syncthreads();
    int e0 = bstart[k], e1 = bstart[k + 1];
    for (int e = e0 + t; e < e1; e += 256)
        atomicAdd(&h[rec1[e] & (BSZ - 1)], 1);
    __syncthreads();
    if (t < BSZ) {                         // wave 0: exclusive scan of 64 counts
        int c = h[t];
        int ps = c;
        #pragma unroll
        for (int off = 1; off < 64; off <<= 1) {
            int u = __shfl_up(ps, off, 64);
            if (t >= off) ps += u;
        }
        int excl = ps - c;
        cur[t] = excl;
        int node = k * BSZ + t;
        if (node < NN) {
            row_ptr[node] = e0 + excl;
            dis[node] = rsqrtf((float)c + 1.0f);
        }
    }
    __syncthreads();
    for (int e = e0 + t; e < e1; e += 256) {
        int r = rec1[e];
        int pos = atomicAdd(&cur[r & (BSZ - 1)], 1);
        rec2[e0 + pos] = r;               // scattered within an ~8KB window: L2-local
    }
    if (k == 0 && t == 0) row_ptr[NN] = NE;
}

// vp1 = dis * (x @ W1)   [NN,512]x[512,16] -> [NN,16]
__global__ __launch_bounds__(256) void k_gemm1(const float* __restrict__ x,
                                               const float* __restrict__ W1,
                                               const float* __restrict__ dis,
                                               float* __restrict__ vp1) {
    __shared__ float ws[128 * FH];
    __shared__ float xs[64 * 132];
    int t = threadIdx.x;
    int row0 = blockIdx.x * 64;
    int r  = t >> 2;
    int jb = (t & 3) * 4;
    float acc0 = 0.f, acc1 = 0.f, acc2 = 0.f, acc3 = 0.f;

    for (int kc = 0; kc < 4; ++kc) {
        __syncthreads();
        {
            const float* wsrc = &W1[kc * 128 * FH];
            *(float4*)&ws[t * 4]        = *(const float4*)&wsrc[t * 4];
            *(float4*)&ws[1024 + t * 4] = *(const float4*)&wsrc[1024 + t * 4];
        }
        for (int it = 0; it < 8; ++it) {
            int idx = it * 1024 + t * 4;
            int rr = idx >> 7;
            int cc = idx & 127;
            int gr = row0 + rr; if (gr >= NN) gr = NN - 1;
            *(float4*)&xs[rr * 132 + cc] = *(const float4*)&x[(size_t)gr * FIN + kc * 128 + cc];
        }
        __syncthreads();
        const float* xrow = &xs[r * 132];
        #pragma unroll 8
        for (int k = 0; k < 128; ++k) {
            float xv = xrow[k];
            float4 w = *(const float4*)&ws[k * FH + jb];
            acc0 += xv * w.x; acc1 += xv * w.y; acc2 += xv * w.z; acc3 += xv * w.w;
        }
    }
    int node = row0 + r;
    if (node < NN) {
        float d = dis[node];
        *(float4*)&vp1[node * FH + jb] = make_float4(d*acc0, d*acc1, d*acc2, d*acc3);
    }
}

// CSR register-accumulating gather over one node's segment.
// 4 lanes per node (q = feature quarter), unroll-4 independent 64B-line gathers.
__device__ __forceinline__ float4 seg_gather(const int* __restrict__ recs,   // LDS
                                             const int* __restrict__ gsrc,   // global fallback (rec2+e0)
                                             int a, int b, int nst,
                                             const float* __restrict__ vp, int q) {
    float4 acc = make_float4(0.f, 0.f, 0.f, 0.f);
    int blds = b < nst ? b : nst;
    int i = a;
    for (; i + 4 <= blds; i += 4) {
        int r0 = recs[i], r1 = recs[i + 1], r2 = recs[i + 2], r3 = recs[i + 3];
        float4 v0 = *(const float4*)&vp[(r0 >> BSH) * FH + q * 4];
        float4 v1 = *(const float4*)&vp[(r1 >> BSH) * FH + q * 4];
        float4 v2 = *(const float4*)&vp[(r2 >> BSH) * FH + q * 4];
        float4 v3 = *(const float4*)&vp[(r3 >> BSH) * FH + q * 4];
        acc.x += v0.x + v1.x + v2.x + v3.x;
        acc.y += v0.y + v1.y + v2.y + v3.y;
        acc.z += v0.z + v1.z + v2.z + v3.z;
        acc.w += v0.w + v1.w + v2.w + v3.w;
    }
    for (; i < blds; ++i) {
        int r0 = recs[i];
        float4 v0 = *(const float4*)&vp[(r0 >> BSH) * FH + q * 4];
        acc.x += v0.x; acc.y += v0.y; acc.z += v0.z; acc.w += v0.w;
    }
    // overflow fallback (bucket > CAP; statistically impossible here but safe)
    for (int j = (a > nst ? a : nst); j < b; ++j) {
        int r0 = gsrc[j];
        float4 v0 = *(const float4*)&vp[(r0 >> BSH) * FH + q * 4];
        acc.x += v0.x; acc.y += v0.y; acc.z += v0.z; acc.w += v0.w;
    }
    return acc;
}

// layer-1: vp2[d] = dis[d] * relu(dis[d]*(sum_s vp1[s] + vp1[d]) + b1)
__global__ __launch_bounds__(256) void k_agg1(const int* __restrict__ rec2,
                                              const int* __restrict__ bstart,
                                              const int* __restrict__ row_ptr,
                                              const float* __restrict__ dis,
                                              const float* __restrict__ vp1,
                                              const float* __restrict__ b1,
                                              float* __restrict__ vp2) {
    __shared__ int recs[CAP];             // 16 KB
    int t = threadIdx.x, k = blockIdx.x;
    int e0 = bstart[k], e1 = bstart[k + 1];
    int len = e1 - e0;
    int nst = len < CAP ? len : CAP;
    for (int i = t; i < nst; i += 256) recs[i] = rec2[e0 + i];
    __syncthreads();                      // no barriers after this: early-exit is safe
    int slot = t >> 2, q = t & 3;
    int node = k * BSZ + slot;
    if (node >= NN) return;
    int a = row_ptr[node] - e0;
    int b = row_ptr[node + 1] - e0;
    float4 acc = seg_gather(recs, rec2 + e0, a, b, nst, vp1, q);
    float dv = dis[node];
    float4 self = *(const float4*)&vp1[node * FH + q * 4];
    float4 bb   = *(const float4*)&b1[q * 4];
    float4 o;
    o.x = dv * fmaxf(dv * (acc.x + self.x) + bb.x, 0.f);
    o.y = dv * fmaxf(dv * (acc.y + self.y) + bb.y, 0.f);
    o.z = dv * fmaxf(dv * (acc.z + self.z) + bb.z, 0.f);
    o.w = dv * fmaxf(dv * (acc.w + self.w) + bb.w, 0.f);
    *(float4*)&vp2[node * FH + q * 4] = o;
}

// layer-2: a16 = dis[d]*(sum_s vp2[s] + vp2[d]); out = relu(a16 @ W2 + b2)
__global__ __launch_bounds__(256) void k_agg2(const int* __restrict__ rec2,
                                              const int* __restrict__ bstart,
                                              const int* __restrict__ row_ptr,
                                              const float* __restrict__ dis,
                                              const float* __restrict__ vp2,
                                              const float* __restrict__ W2,
                                              const float* __restrict__ b2,
                                              float* __restrict__ out) {
    __shared__ int   recs[CAP];           // 16 KB
    __shared__ float a16[BSZ * FH];       // 4 KB
    __shared__ float ws[FH * FOUT];       // 4 KB
    int t = threadIdx.x, k = blockIdx.x;
    *(float4*)&ws[t * 4] = *(const float4*)&W2[t * 4];   // 256*4 = 1024 = FH*FOUT
    int e0 = bstart[k], e1 = bstart[k + 1];
    int len = e1 - e0;
    int nst = len < CAP ? len : CAP;
    for (int i = t; i < nst; i += 256) recs[i] = rec2[e0 + i];
    __syncthreads();
    int slot = t >> 2, q = t & 3;
    int node = k * BSZ + slot;
    float4 r = make_float4(0.f, 0.f, 0.f, 0.f);
    if (node < NN) {
        int a = row_ptr[node] - e0;
        int b = row_ptr[node + 1] - e0;
        float4 acc = seg_gather(recs, rec2 + e0, a, b, nst, vp2, q);
        float dv = dis[node];
        float4 self = *(const float4*)&vp2[node * FH + q * 4];
        r.x = dv * (acc.x + self.x);
        r.y = dv * (acc.y + self.y);
        r.z = dv * (acc.z + self.z);
        r.w = dv * (acc.w + self.w);
    }
    *(float4*)&a16[slot * FH + q * 4] = r;
    __syncthreads();
    // GEMM: 64 output lanes x 4 nodes/pass; W2 column hoisted to registers
    int j = t & 63;
    float bj = b2[j];
    float wreg[FH];
    #pragma unroll
    for (int kk = 0; kk < FH; ++kk) wreg[kk] = ws[kk * FOUT + j];
    for (int n = t >> 6; n < BSZ; n += 4) {
        int node2 = k * BSZ + n;
        if (node2 >= NN) break;
        const float* ar = &a16[n * FH];
        float s = 0.f;
        #pragma unroll
        for (int kk = 0; kk < FH; ++kk) s += ar[kk] * wreg[kk];
        out[node2 * FOUT + j] = fmaxf(s + bj, 0.f);
    }
}

extern "C" void kernel_launch(void* const* d_in, const int* in_sizes, int n_in,
                              void* d_out, int out_size, void* d_ws, size_t ws_size,
                              hipStream_t stream) {
    const float* x  = (const float*)d_in[0];
    const int*   ei = (const int*)d_in[1];
    const float* W1 = (const float*)d_in[2];
    const float* b1 = (const float*)d_in[3];
    const float* W2 = (const float*)d_in[4];
    const float* b2 = (const float*)d_in[5];
    float* out = (float*)d_out;

    // workspace (~29.6 MB). rec1's 12.8MB is dead after k_sort2 and is reused
    // for vp1 (6.4MB) + vp2 (6.4MB): k_gemm1 writes vp1 strictly after k_sort2
    // reads rec1 (stream-ordered).
    char* p = (char*)d_ws;
    int*   M       = (int*)p;    p += (size_t)K * NB * 4;      // 3.2 MB
    int*   btot    = (int*)p;    p += 2048 * 4;
    int*   bstart  = (int*)p;    p += 2048 * 4;
    char*  bufA    = p;          p += (size_t)NE * 4;          // 12.8 MB (rec1 -> vp1+vp2)
    int*   rec2    = (int*)p;    p += (size_t)NE * 4;          // 12.8 MB
    int*   row_ptr = (int*)p;    p += 100032 * 4;              // 0.4 MB
    float* dis     = (float*)p;  p += 100032 * 4;              // 0.4 MB

    int*   rec1 = (int*)bufA;
    float* vp1  = (float*)bufA;
    float* vp2  = (float*)(bufA + (size_t)NN * FH * 4);

    k_cnt     <<<NB, 256, 0, stream>>>(ei, M);
    k_scanM   <<<K, 256, 0, stream>>>(M, btot);
    k_scanB   <<<1, 1024, 0, stream>>>(btot, bstart);
    k_scatter2<<<NB, 256, 0, stream>>>(ei, M, bstart, rec1);
    k_sort2   <<<K, 256, 0, stream>>>(rec1, bstart, rec2, row_ptr, dis);

    k_gemm1   <<<(NN + 63) / 64, 256, 0, stream>>>(x, W1, dis, vp1);
    k_agg1    <<<K, 256, 0, stream>>>(rec2, bstart, row_ptr, dis, vp1, b1, vp2);
    k_agg2    <<<K, 256, 0, stream>>>(rec2, bstart, row_ptr, dis, vp2, W2, b2, out);
}